// Round 5
// baseline (124503.601 us; speedup 1.0000x reference)
//
#include <hip/hip_runtime.h>
#include <hip/hip_cooperative_groups.h>
#include <cstddef>

namespace cg = cooperative_groups;

#define T_STEPS 16384
#define E_DIM   1024
#define H_DIM   1024
#define G4      4096

#define NWG_REC   128       // recurrence workgroups (hot loop)
#define NWG_RELAY 16        // per-XCD relay candidates (>=2 per XCD expected)
#define NWG_GEMM  32        // dedicated GEMM producer workgroups
#define NWG       (NWG_REC + NWG_RELAY + NWG_GEMM)
#define NTH       512       // 8 waves per wg
#define EPW       8         // h elements per recurrence wg (one per wave)
#define CH        256       // timesteps per GEMM chunk; ring of 2 => 8MiB
#define NCHUNK    (T_STEPS / CH)
#define TKc       32
#define NXCD      8
#define LOCAL_SPIN 64       // bounded local-L2 poll rounds before direct fallback

#define LDA(p)    __hip_atomic_load((p), __ATOMIC_RELAXED, __HIP_MEMORY_SCOPE_AGENT)
#define STA(p, v) __hip_atomic_store((p), (v), __ATOMIC_RELAXED, __HIP_MEMORY_SCOPE_AGENT)
// workgroup-scope relaxed store: plain global_store (no sc bits) -> lands dirty
// in the XCD-local L2 (L1 is write-through/no-allocate), 8B-atomic (no tearing).
#define STL(p, v) __hip_atomic_store((p), (v), __ATOMIC_RELAXED, __HIP_MEMORY_SCOPE_WORKGROUP)

typedef unsigned int uintx4 __attribute__((ext_vector_type(4)));

// DPP xor-partner add helpers: quad_perm 0xB1 = xor1, 0x4E = xor2,
// row_ror:8 (0x128) = xor8 within a 16-lane row. Bitwise-identical pair sums
// to __shfl_xor at the same offsets, but VALU-speed (no ds op).
template <int CTRL>
__device__ __forceinline__ float dpp_xor(float v) {
    return __int_as_float(
        __builtin_amdgcn_update_dpp(0, __float_as_int(v), CTRL, 0xF, 0xF, true));
}

__device__ __forceinline__ float bcast_lane(float v, int l) {
    return __int_as_float(__builtin_amdgcn_readlane(__float_as_int(v), l));
}

__device__ __forceinline__ int read_xcd() {
    unsigned x;
    asm volatile("s_getreg_b32 %0, hwreg(HW_REG_XCC_ID)" : "=s"(x));
    return (int)(x & (NXCD - 1));
}

// h exchange: h_t at hslot[(t&3)<<10 | j], value ((t+1)<<32)|bits.
// Tags 1..16385; stale/poison (0xAAAAAAAA) tags never match.
//
// RELAY FAN-OUT (new): per XCD, one relay WG streams validated hslot records
// (LLC, sc0 sc1) into xbuf[xcd] via 8B workgroup-scope stores (dirty in the
// local L2). Consumers on that XCD poll xbuf[xcd] with sc0-only 16B loads
// (L1 bypass, local-L2 hit) -> LLC poll multicast drops 128 WGs -> 8 WGs, and
// consumer RTT drops ~1500(contended LLC) -> ~250 (local L2).
// Safety: every record self-validates by tag; consumers on an unclaimed XCD,
// or after LOCAL_SPIN failed local rounds, use the proven direct LLC poll
// (single asm block, load+vmcnt(0)) -> termination guaranteed regardless of
// WG->XCD mapping. Slot reuse (4 generations) safe: relay reaches gen t+4
// only after every consumer has passed gen t+2 (global lockstep argument).

__global__ __launch_bounds__(NTH) void lstm_fused_kernel(
    const float* __restrict__ Xs, const float* __restrict__ Wih,
    const float* __restrict__ Whh, const float* __restrict__ bih,
    const float* __restrict__ bhh, const int* __restrict__ ys,
    float* __restrict__ xgc,                 // 2 * CH * 4096 floats (ring)
    unsigned long long* __restrict__ hslot,  // 4*1024 packed entries (LLC home)
    float* __restrict__ partials,            // NWG_REC*T
    float* __restrict__ hy,                  // T
    float* __restrict__ wsum,                // 32
    int*   __restrict__ flags,               // [0..63]=ready [64..127]=done [128..135]=claim
    unsigned long long* __restrict__ xbuf,   // NXCD * 4*1024 relay mirrors
    float* __restrict__ out)                 // 1
{
    cg::grid_group grid = cg::this_grid();
    const int w    = blockIdx.x;
    const int tid  = threadIdx.x;
    const int lane = tid & 63;
    const int j    = tid >> 6;        // wave index

    __shared__ float hs[2][H_DIM];    // double-buffered h stage
    __shared__ float ered[16][EPW];   // exp partials ring (16 steps deep)
    __shared__ float red[8];
    __shared__ float As[TKc][68];
    __shared__ float Bs[TKc][132];

    int* chunk_ready = flags;
    int* cons_done   = flags + 64;
    int* relay_claim = flags + 128;   // [NXCD]

    // flags must start at 0 regardless of workspace poison / previous run
    if (w == 0 && tid < 160) STA(&flags[tid], 0);
    grid.sync();

    const int myxcd = read_xcd();

    // ---- relay election: candidates CAS-claim their own XCD ----
    if (w >= NWG_REC && w < NWG_REC + NWG_RELAY && tid == 0) {
        int expect = 0;
        __hip_atomic_compare_exchange_strong(
            &relay_claim[myxcd], &expect, w - NWG_REC + 1,
            __ATOMIC_RELAXED, __ATOMIC_RELAXED, __HIP_MEMORY_SCOPE_AGENT);
    }
    __threadfence();
    grid.sync();

    if (w >= NWG_REC + NWG_RELAY) {
        // ================= dedicated GEMM producers =================
        const int g    = w - NWG_REC - NWG_RELAY;   // 0..31 : col tile (128 cols)
        const int n0   = g * 128;
        const int tx4  = (tid & 31) * 4;
        const int ty4  = (tid >> 5) * 4;
        const int lrow = tid >> 3;
        const int lkg  = (tid & 7) * 4;

        float4 bias_v;
        {
            const float4 bi = *(const float4*)&bih[n0 + tx4];
            const float4 bh = *(const float4*)&bhh[n0 + tx4];
            bias_v.x = bi.x + bh.x; bias_v.y = bi.y + bh.y;
            bias_v.z = bi.z + bh.z; bias_v.w = bi.w + bh.w;
        }

        for (int c = 0; c < NCHUNK; ++c) {
            if (c >= 2) {   // ring slot c&1 free only when chunk c-2 consumed
                if (tid == 0) while (LDA(&cons_done[c - 2]) < NWG_REC) {}
                __syncthreads();
            }
            const int t0 = c * CH;
            float* xg = xgc + (size_t)(c & 1) * ((size_t)CH * G4);

#pragma unroll 1
            for (int rep = 0; rep < 4; ++rep) {    // 4 row tiles of 64 = 256 rows
                float acc[4][4];
#pragma unroll
                for (int i = 0; i < 4; ++i)
#pragma unroll
                    for (int jj = 0; jj < 4; ++jj) acc[i][jj] = 0.f;

                const float* Arow = Xs + (size_t)(t0 + rep * 64 + lrow) * E_DIM + lkg;

                for (int kc = 0; kc < E_DIM; kc += TKc) {
                    __syncthreads();
                    float4 av = *(const float4*)(Arow + kc);
                    As[lkg + 0][lrow] = av.x; As[lkg + 1][lrow] = av.y;
                    As[lkg + 2][lrow] = av.z; As[lkg + 3][lrow] = av.w;
#pragma unroll
                    for (int r2 = 0; r2 < 2; ++r2) {
                        int br = r2 * 64 + lrow;
                        float4 bv = *(const float4*)&Wih[(size_t)(n0 + br) * E_DIM + kc + lkg];
                        Bs[lkg + 0][br] = bv.x; Bs[lkg + 1][br] = bv.y;
                        Bs[lkg + 2][br] = bv.z; Bs[lkg + 3][br] = bv.w;
                    }
                    __syncthreads();
#pragma unroll
                    for (int kk = 0; kk < TKc; ++kk) {
                        float4 a = *(const float4*)&As[kk][ty4];
                        float4 b = *(const float4*)&Bs[kk][tx4];
                        acc[0][0] = fmaf(a.x, b.x, acc[0][0]); acc[0][1] = fmaf(a.x, b.y, acc[0][1]);
                        acc[0][2] = fmaf(a.x, b.z, acc[0][2]); acc[0][3] = fmaf(a.x, b.w, acc[0][3]);
                        acc[1][0] = fmaf(a.y, b.x, acc[1][0]); acc[1][1] = fmaf(a.y, b.y, acc[1][1]);
                        acc[1][2] = fmaf(a.y, b.z, acc[1][2]); acc[1][3] = fmaf(a.y, b.w, acc[1][3]);
                        acc[2][0] = fmaf(a.z, b.x, acc[2][0]); acc[2][1] = fmaf(a.z, b.y, acc[2][1]);
                        acc[2][2] = fmaf(a.z, b.z, acc[2][2]); acc[2][3] = fmaf(a.z, b.w, acc[2][3]);
                        acc[3][0] = fmaf(a.w, b.x, acc[3][0]); acc[3][1] = fmaf(a.w, b.y, acc[3][1]);
                        acc[3][2] = fmaf(a.w, b.z, acc[3][2]); acc[3][3] = fmaf(a.w, b.w, acc[3][3]);
                    }
                }
#pragma unroll
                for (int i = 0; i < 4; ++i) {
                    int lr = rep * 64 + ty4 + i;   // chunk-local row
                    float4 ov;
                    ov.x = acc[i][0] + bias_v.x; ov.y = acc[i][1] + bias_v.y;
                    ov.z = acc[i][2] + bias_v.z; ov.w = acc[i][3] + bias_v.w;
                    *(float4*)&xg[(size_t)lr * G4 + n0 + tx4] = ov;
                }
            }
            __syncthreads();   // drains all threads' xg stores to L2
            if (tid == 0)
                __hip_atomic_fetch_add(&chunk_ready[c], 1,
                                       __ATOMIC_RELEASE, __HIP_MEMORY_SCOPE_AGENT);
        }
    } else if (w >= NWG_REC) {
        // ================= relay workgroups =================
        if (LDA(&relay_claim[myxcd]) == w - NWG_REC + 1) {
            // winner: stream hslot -> xbuf[myxcd] for my 2 entries, all T gens
            unsigned long long* xb = xbuf + (size_t)myxcd * (4 * H_DIM);
#pragma unroll 1
            for (int t = 0; t < T_STEPS; ++t) {
                const unsigned htag = (unsigned)(t + 1);
                const size_t off = ((size_t)(t & 3) << 10) + 2 * tid;
                const unsigned long long* hp = hslot + off;
                uintx4 pv;
                do {
                    asm volatile(
                        "global_load_dwordx4 %0, %1, off sc0 sc1\n\t"
                        "s_waitcnt vmcnt(0)"
                        : "=&v"(pv) : "v"(hp) : "memory");
                } while (pv.y != htag || pv.w != htag);
                // two 8B atomic halves (no tearing), plain-store path -> local L2
                STL(&xb[off],     ((unsigned long long)pv.y << 32) | pv.x);
                STL(&xb[off + 1], ((unsigned long long)pv.w << 32) | pv.z);
            }
        }
        // losers: idle to the final grid syncs
    } else {
        // ================= recurrence workgroups =================
        const int gj = w * EPW + j;     // global h element this wave owns

        const bool use_relay = (LDA(&relay_claim[myxcd]) != 0);
        const unsigned long long* lbase = xbuf + (size_t)myxcd * (4 * H_DIM);

        // ---- W_hh rows for the 4 gates of element gj; k = lane + 64m ----
        float Wreg[4][16];
#pragma unroll
        for (int g = 0; g < 4; ++g) {
            const float* wr = Whh + (size_t)(g * H_DIM + gj) * H_DIM + lane;
#pragma unroll
            for (int m = 0; m < 16; ++m) Wreg[g][m] = wr[m << 6];
        }

        float c_state = 0.f;                              // replicated in all lanes
        if (lane == 0) STA(&hslot[gj], 1ull << 32);       // publish h_0 = 0 (tag 1)

        float xv0 = 0.f, xv1 = 0.f, xv2 = 0.f, xv3 = 0.f; // xg broadcast (uniform)
        int   yt = 0, ytn = 0;
        if (lane == 0) yt = ys[0];                        // prefetched thereafter

        for (int c = 0; c < NCHUNK; ++c) {
            const int t0 = c * CH;
            const float* xg = xgc + (size_t)(c & 1) * ((size_t)CH * G4);

            // wait for producers; per-thread acquire invalidates stale cache lines
            if (tid == 0) while (LDA(&chunk_ready[c]) < NWG_GEMM) {}
            __syncthreads();
            (void)__hip_atomic_load(&chunk_ready[c],
                                    __ATOMIC_ACQUIRE, __HIP_MEMORY_SCOPE_AGENT);

            // xg for first step of chunk (lanes 0..3 load, broadcast to all)
            {
                float xq = 0.f;
                if (lane < 4) xq = xg[lane * H_DIM + gj];
                xv0 = bcast_lane(xq, 0); xv1 = bcast_lane(xq, 1);
                xv2 = bcast_lane(xq, 2); xv3 = bcast_lane(xq, 3);
            }

            for (int lt = 0; lt < CH; ++lt) {
                const int t = t0 + lt;
                const int p = t & 1;

                // ---- poll own h pair: local-L2 mirror first, LLC fallback ----
                {
                    const unsigned htag = (unsigned)(t + 1);
                    const size_t off = ((size_t)(t & 3) << 10) + 2 * tid;
                    const unsigned long long* hp = hslot + off;
                    unsigned hv0u, hv1u;
                    bool got = false;
                    if (use_relay) {
                        const unsigned long long* xp = lbase + off;
                        for (int r = 0; r < LOCAL_SPIN; ++r) {
                            uintx4 pv;
                            asm volatile(
                                "global_load_dwordx4 %0, %1, off sc0\n\t"
                                "s_waitcnt vmcnt(0)"
                                : "=&v"(pv) : "v"(xp) : "memory");
                            if (pv.y == htag && pv.w == htag) {
                                hv0u = pv.x; hv1u = pv.z; got = true; break;
                            }
                        }
                    }
                    if (!got) {
                        // proven direct LLC poll (guaranteed termination)
                        uintx4 pv;
                        do {
                            asm volatile(
                                "global_load_dwordx4 %0, %1, off sc0 sc1\n\t"
                                "s_waitcnt vmcnt(0)"
                                : "=&v"(pv) : "v"(hp) : "memory");
                        } while (pv.y != htag || pv.w != htag);
                        hv0u = pv.x; hv1u = pv.z;
                    }
                    hs[p][2 * tid]     = __uint_as_float(hv0u);
                    hs[p][2 * tid + 1] = __uint_as_float(hv1u);
                }
                __syncthreads();   // the only barrier per step

                // ---- batched exp-partial flush: every 8 steps, rotating wave ----
                if ((t & 7) == 0 && t >= 8 && j == ((t >> 3) & 7)) {
                    const int b = t - 8;
                    float e = ered[(b & 15) + (lane >> 3)][lane & 7];
                    e += __shfl_xor(e, 1);
                    e += __shfl_xor(e, 2);
                    e += __shfl_xor(e, 4);
                    if ((lane & 7) == 0)
                        partials[(size_t)w * T_STEPS + b + (lane >> 3)] = e;
                }

                // ---- prefetch next step's xg and ys (off critical path) ----
                float xn = 0.f;
                if (lane < 4 && lt + 1 < CH)
                    xn = xg[(size_t)(lt + 1) * G4 + lane * H_DIM + gj];
                ytn = yt;
                if (lane == 0) {
                    int tn = (t + 1 < T_STEPS) ? t + 1 : t;
                    ytn = ys[tn];
                }

                // ---- matvec: 4 gate rows of gj ----
                float a0 = 0.f, a1 = 0.f, a2 = 0.f, a3 = 0.f;
#pragma unroll
                for (int m = 0; m < 16; ++m) {
                    float hvv = hs[p][lane + (m << 6)];
                    a0 = fmaf(Wreg[0][m], hvv, a0);
                    a1 = fmaf(Wreg[1][m], hvv, a1);
                    a2 = fmaf(Wreg[2][m], hvv, a2);
                    a3 = fmaf(Wreg[3][m], hvv, a3);
                }
                // xor-tree reduce: 32,16 via shfl; 8 via DPP row_ror:8; 4 via
                // shfl; 2,1 via DPP quad_perm. Same pairs, same order ->
                // bitwise identical; all lanes end with the full sums.
                a0 += __shfl_xor(a0, 32); a1 += __shfl_xor(a1, 32);
                a2 += __shfl_xor(a2, 32); a3 += __shfl_xor(a3, 32);
                a0 += __shfl_xor(a0, 16); a1 += __shfl_xor(a1, 16);
                a2 += __shfl_xor(a2, 16); a3 += __shfl_xor(a3, 16);
                a0 += dpp_xor<0x128>(a0); a1 += dpp_xor<0x128>(a1);
                a2 += dpp_xor<0x128>(a2); a3 += dpp_xor<0x128>(a3);
                a0 += __shfl_xor(a0, 4);  a1 += __shfl_xor(a1, 4);
                a2 += __shfl_xor(a2, 4);  a3 += __shfl_xor(a3, 4);
                a0 += dpp_xor<0x4E>(a0);  a1 += dpp_xor<0x4E>(a1);
                a2 += dpp_xor<0x4E>(a2);  a3 += dpp_xor<0x4E>(a3);
                a0 += dpp_xor<0xB1>(a0);  a1 += dpp_xor<0xB1>(a1);
                a2 += dpp_xor<0xB1>(a2);  a3 += dpp_xor<0xB1>(a3);

                // ---- all-lane activations (bitwise same formulas) ----
                float x0 = a0 + xv0;
                float x1 = a1 + xv1;
                float x2 = a2 + xv2;
                float x3 = a3 + xv3;
                float ii  = 1.f / (1.f + __expf(-x0));
                float ff  = 1.f / (1.f + __expf(-x1));
                float sg2 = 1.f / (1.f + __expf(-2.f * x2));
                float gg  = fmaf(sg2, 2.f, -1.f);
                float oo  = 1.f / (1.f + __expf(-x3));
                c_state   = fmaf(ff, c_state, ii * gg);
                float tc  = 2.f / (1.f + __expf(-2.f * c_state)) - 1.f;
                float h   = oo * tc;

                if (lane == 0) {
                    // publish ASAP: h_{t+1} tag t+2, slot (t+1)&3
                    STA(&hslot[((size_t)((t + 1) & 3) << 10) + gj],
                        ((unsigned long long)(unsigned)(t + 2) << 32) |
                        (unsigned long long)__float_as_uint(h));
                    ered[t & 15][j] = __expf(h);   // h in (-1,1): exp safe
                    if (gj == yt) hy[t] = h;
                }
                yt = ytn;
                // broadcast next step's xg (uniform via readlane, no ds op)
                xv0 = bcast_lane(xn, 0); xv1 = bcast_lane(xn, 1);
                xv2 = bcast_lane(xn, 2); xv3 = bcast_lane(xn, 3);
            }

            __syncthreads();   // all this wg's xg reads for chunk c retired
            if (tid == 0)
                __hip_atomic_fetch_add(&cons_done[c], 1,
                                       __ATOMIC_RELAXED, __HIP_MEMORY_SCOPE_AGENT);
        }

        // final exp-partial flush (steps T-8 .. T-1)
        __syncthreads();
        if (j == 0) {
            const int b = T_STEPS - 8;
            float e = ered[(b & 15) + (lane >> 3)][lane & 7];
            e += __shfl_xor(e, 1);
            e += __shfl_xor(e, 2);
            e += __shfl_xor(e, 4);
            if ((lane & 7) == 0)
                partials[(size_t)w * T_STEPS + b + (lane >> 3)] = e;
        }
    }

    __threadfence();
    grid.sync();

    // ================= loss: wgs 0..31 cover all T =================
    if (w < 32) {
        int t = w * NTH + tid;
        float s = 0.f;
        for (int i = 0; i < NWG_REC; ++i) s += partials[(size_t)i * T_STEPS + t];
        float val = logf(s) - hy[t];
#pragma unroll
        for (int off = 32; off >= 1; off >>= 1) val += __shfl_xor(val, off);
        if (lane == 0) red[tid >> 6] = val;
        __syncthreads();
        if (tid == 0) {
            float s2 = 0.f;
#pragma unroll
            for (int i = 0; i < 8; ++i) s2 += red[i];
            wsum[w] = s2;
        }
    }
    __threadfence();
    grid.sync();
    if (w == 0 && tid == 0) {
        float s = 0.f;
        for (int i = 0; i < 32; ++i) s += wsum[i];
        out[0] = s;
    }
}

// ---------------- launch ----------------
extern "C" void kernel_launch(void* const* d_in, const int* in_sizes, int n_in,
                              void* d_out, int out_size, void* d_ws, size_t ws_size,
                              hipStream_t stream)
{
    const float* Xs  = (const float*)d_in[0];
    const float* Wih = (const float*)d_in[1];
    const float* Whh = (const float*)d_in[2];
    const float* bih = (const float*)d_in[3];
    const float* bhh = (const float*)d_in[4];
    const int*   ys  = (const int*)d_in[5];

    // workspace: 8MB xgc ring + 32KB hslot + 8MB partials + 64KB hy + 128B wsum
    //            + 1KB flags + 256KB xbuf ~= 16.4 MiB
    float* xgc                = (float*)d_ws;
    unsigned long long* hslot = (unsigned long long*)(xgc + 2 * (size_t)CH * G4);
    float* partials           = (float*)(hslot + 4 * H_DIM);
    float* hy                 = partials + (size_t)NWG_REC * T_STEPS;
    float* wsum               = hy + T_STEPS;
    int*   flags              = (int*)(wsum + 32);
    unsigned long long* xbuf  = (unsigned long long*)(flags + 256);
    float* out                = (float*)d_out;

    void* args[] = {(void*)&Xs, (void*)&Wih, (void*)&Whh, (void*)&bih, (void*)&bhh,
                    (void*)&ys, (void*)&xgc, (void*)&hslot, (void*)&partials,
                    (void*)&hy, (void*)&wsum, (void*)&flags, (void*)&xbuf, (void*)&out};
    hipLaunchCooperativeKernel((void*)lstm_fused_kernel,
                               dim3(NWG), dim3(NTH), args, 0, stream);
}

// Round 6
// 50716.492 us; speedup vs baseline: 2.4549x; 2.4549x over previous
//
#include <hip/hip_runtime.h>
#include <hip/hip_cooperative_groups.h>
#include <cstddef>

namespace cg = cooperative_groups;

#define T_STEPS 16384
#define E_DIM   1024
#define H_DIM   1024
#define G4      4096

#define NWG_REC  64         // recurrence workgroups (hot loop)
#define NWG_GEMM 32         // dedicated GEMM producer workgroups
#define NWG      (NWG_REC + NWG_GEMM)
#define NTH      512        // 8 waves per wg
#define EPW      16         // h elements per recurrence wg (TWO per wave)
#define CH       256        // timesteps per GEMM chunk; ring of 2 => 8MiB
#define NCHUNK   (T_STEPS / CH)
#define TKc      32

#define LDA(p)    __hip_atomic_load((p), __ATOMIC_RELAXED, __HIP_MEMORY_SCOPE_AGENT)
#define STA(p, v) __hip_atomic_store((p), (v), __ATOMIC_RELAXED, __HIP_MEMORY_SCOPE_AGENT)

typedef unsigned int uintx4 __attribute__((ext_vector_type(4)));

// DPP xor-partner add helpers: quad_perm 0xB1 = xor1, 0x4E = xor2,
// row_ror:8 (0x128) = xor8 within a 16-lane row. Bitwise-identical pair sums
// to __shfl_xor at the same offsets, but VALU-speed (no ds op).
template <int CTRL>
__device__ __forceinline__ float dpp_xor(float v) {
    return __int_as_float(
        __builtin_amdgcn_update_dpp(0, __float_as_int(v), CTRL, 0xF, 0xF, true));
}

__device__ __forceinline__ float bcast_lane(float v, int l) {
    return __int_as_float(__builtin_amdgcn_readlane(__float_as_int(v), l));
}

// h exchange: h_t at hslot[(t&3)<<10 | j], value ((t+1)<<32)|bits.
// Tags 1..16385; stale/poison tags never match. Poll = round-2 proven serial
// single-asm-block dwordx4 sc0 sc1 (load + vmcnt(0) in ONE statement).
// TOPOLOGY CHANGE vs round 2: 64 consumer WGs (was 128), each wave owns TWO
// adjacent h elements -> LLC multicast per line halves (64 readers) and the
// publish count halves (512x 16B stores, each 8B half self-validating).

__global__ __launch_bounds__(NTH) void lstm_fused_kernel(
    const float* __restrict__ Xs, const float* __restrict__ Wih,
    const float* __restrict__ Whh, const float* __restrict__ bih,
    const float* __restrict__ bhh, const int* __restrict__ ys,
    float* __restrict__ xgc,                 // 2 * CH * 4096 floats (ring)
    unsigned long long* __restrict__ hslot,  // 4*1024 packed entries
    float* __restrict__ partials,            // NWG_REC*T
    float* __restrict__ hy,                  // T
    float* __restrict__ wsum,                // 32
    int*   __restrict__ flags,               // [0..63]=chunk_ready [64..127]=cons_done
    float* __restrict__ out)                 // 1
{
    cg::grid_group grid = cg::this_grid();
    const int w    = blockIdx.x;
    const int tid  = threadIdx.x;
    const int lane = tid & 63;
    const int j    = tid >> 6;        // wave index

    __shared__ float hs[2][H_DIM];    // double-buffered h stage
    __shared__ float ered[16][EPW];   // exp partials ring (16 steps deep)
    __shared__ float red[8];
    __shared__ float As[TKc][68];
    __shared__ float Bs[TKc][132];

    int* chunk_ready = flags;
    int* cons_done   = flags + 64;

    // flags must start at 0 regardless of workspace poison / previous run
    if (w == 0 && tid < 128) STA(&flags[tid], 0);
    grid.sync();

    if (w >= NWG_REC) {
        // ================= dedicated GEMM producers =================
        const int g    = w - NWG_REC;       // 0..31 : col tile (128 cols)
        const int n0   = g * 128;
        const int tx4  = (tid & 31) * 4;
        const int ty4  = (tid >> 5) * 4;
        const int lrow = tid >> 3;
        const int lkg  = (tid & 7) * 4;

        float4 bias_v;
        {
            const float4 bi = *(const float4*)&bih[n0 + tx4];
            const float4 bh = *(const float4*)&bhh[n0 + tx4];
            bias_v.x = bi.x + bh.x; bias_v.y = bi.y + bh.y;
            bias_v.z = bi.z + bh.z; bias_v.w = bi.w + bh.w;
        }

        for (int c = 0; c < NCHUNK; ++c) {
            if (c >= 2) {   // ring slot c&1 free only when chunk c-2 consumed
                if (tid == 0) while (LDA(&cons_done[c - 2]) < NWG_REC) {}
                __syncthreads();
            }
            const int t0 = c * CH;
            float* xg = xgc + (size_t)(c & 1) * ((size_t)CH * G4);

#pragma unroll 1
            for (int rep = 0; rep < 4; ++rep) {    // 4 row tiles of 64 = 256 rows
                float acc[4][4];
#pragma unroll
                for (int i = 0; i < 4; ++i)
#pragma unroll
                    for (int jj = 0; jj < 4; ++jj) acc[i][jj] = 0.f;

                const float* Arow = Xs + (size_t)(t0 + rep * 64 + lrow) * E_DIM + lkg;

                for (int kc = 0; kc < E_DIM; kc += TKc) {
                    __syncthreads();
                    float4 av = *(const float4*)(Arow + kc);
                    As[lkg + 0][lrow] = av.x; As[lkg + 1][lrow] = av.y;
                    As[lkg + 2][lrow] = av.z; As[lkg + 3][lrow] = av.w;
#pragma unroll
                    for (int r2 = 0; r2 < 2; ++r2) {
                        int br = r2 * 64 + lrow;
                        float4 bv = *(const float4*)&Wih[(size_t)(n0 + br) * E_DIM + kc + lkg];
                        Bs[lkg + 0][br] = bv.x; Bs[lkg + 1][br] = bv.y;
                        Bs[lkg + 2][br] = bv.z; Bs[lkg + 3][br] = bv.w;
                    }
                    __syncthreads();
#pragma unroll
                    for (int kk = 0; kk < TKc; ++kk) {
                        float4 a = *(const float4*)&As[kk][ty4];
                        float4 b = *(const float4*)&Bs[kk][tx4];
                        acc[0][0] = fmaf(a.x, b.x, acc[0][0]); acc[0][1] = fmaf(a.x, b.y, acc[0][1]);
                        acc[0][2] = fmaf(a.x, b.z, acc[0][2]); acc[0][3] = fmaf(a.x, b.w, acc[0][3]);
                        acc[1][0] = fmaf(a.y, b.x, acc[1][0]); acc[1][1] = fmaf(a.y, b.y, acc[1][1]);
                        acc[1][2] = fmaf(a.y, b.z, acc[1][2]); acc[1][3] = fmaf(a.y, b.w, acc[1][3]);
                        acc[2][0] = fmaf(a.z, b.x, acc[2][0]); acc[2][1] = fmaf(a.z, b.y, acc[2][1]);
                        acc[2][2] = fmaf(a.z, b.z, acc[2][2]); acc[2][3] = fmaf(a.z, b.w, acc[2][3]);
                        acc[3][0] = fmaf(a.w, b.x, acc[3][0]); acc[3][1] = fmaf(a.w, b.y, acc[3][1]);
                        acc[3][2] = fmaf(a.w, b.z, acc[3][2]); acc[3][3] = fmaf(a.w, b.w, acc[3][3]);
                    }
                }
#pragma unroll
                for (int i = 0; i < 4; ++i) {
                    int lr = rep * 64 + ty4 + i;   // chunk-local row
                    float4 ov;
                    ov.x = acc[i][0] + bias_v.x; ov.y = acc[i][1] + bias_v.y;
                    ov.z = acc[i][2] + bias_v.z; ov.w = acc[i][3] + bias_v.w;
                    *(float4*)&xg[(size_t)lr * G4 + n0 + tx4] = ov;
                }
            }
            __syncthreads();   // drains all threads' xg stores to L2
            if (tid == 0)
                __hip_atomic_fetch_add(&chunk_ready[c], 1,
                                       __ATOMIC_RELEASE, __HIP_MEMORY_SCOPE_AGENT);
        }
    } else {
        // ================= recurrence workgroups =================
        const int gj0 = w * EPW + 2 * j;   // wave owns elements gj0, gj0+1

        // ---- W_hh rows for the 4 gates of both elements; k = lane + 64m ----
        float Wreg0[4][16], Wreg1[4][16];
#pragma unroll
        for (int g = 0; g < 4; ++g) {
            const float* wr0 = Whh + (size_t)(g * H_DIM + gj0) * H_DIM + lane;
            const float* wr1 = wr0 + H_DIM;
#pragma unroll
            for (int m = 0; m < 16; ++m) { Wreg0[g][m] = wr0[m << 6]; Wreg1[g][m] = wr1[m << 6]; }
        }

        float c0s = 0.f, c1s = 0.f;                       // replicated in all lanes
        if (lane == 0) {                                  // publish h_0 = 0 (tag 1)
            STA(&hslot[gj0],     1ull << 32);
            STA(&hslot[gj0 + 1], 1ull << 32);
        }

        float xv0 = 0.f, xv1 = 0.f, xv2 = 0.f, xv3 = 0.f; // xg gates, element 0
        float xv4 = 0.f, xv5 = 0.f, xv6 = 0.f, xv7 = 0.f; // xg gates, element 1
        int   yt = 0, ytn = 0;
        if (lane == 0) yt = ys[0];                        // prefetched thereafter

        for (int c = 0; c < NCHUNK; ++c) {
            const int t0 = c * CH;
            const float* xg = xgc + (size_t)(c & 1) * ((size_t)CH * G4);

            // wait for producers; per-thread acquire invalidates stale cache lines
            if (tid == 0) while (LDA(&chunk_ready[c]) < NWG_GEMM) {}
            __syncthreads();
            (void)__hip_atomic_load(&chunk_ready[c],
                                    __ATOMIC_ACQUIRE, __HIP_MEMORY_SCOPE_AGENT);

            // xg for first step of chunk (lanes 0..7: gate=lane&3, elem=lane>>2)
            {
                float xq = 0.f;
                if (lane < 8) xq = xg[(lane & 3) * H_DIM + gj0 + (lane >> 2)];
                xv0 = bcast_lane(xq, 0); xv1 = bcast_lane(xq, 1);
                xv2 = bcast_lane(xq, 2); xv3 = bcast_lane(xq, 3);
                xv4 = bcast_lane(xq, 4); xv5 = bcast_lane(xq, 5);
                xv6 = bcast_lane(xq, 6); xv7 = bcast_lane(xq, 7);
            }

            for (int lt = 0; lt < CH; ++lt) {
                const int t = t0 + lt;
                const int p = t & 1;

                // ---- poll own h pair: round-2 proven serial dwordx4 ----
                {
                    const unsigned htag = (unsigned)(t + 1);
                    const unsigned long long* hp =
                        hslot + ((size_t)(t & 3) << 10) + 2 * tid;
                    uintx4 pv;
                    do {
                        asm volatile(
                            "global_load_dwordx4 %0, %1, off sc0 sc1\n\t"
                            "s_waitcnt vmcnt(0)"
                            : "=&v"(pv) : "v"(hp) : "memory");
                    } while (pv.y != htag || pv.w != htag);
                    hs[p][2 * tid]     = __uint_as_float(pv.x);
                    hs[p][2 * tid + 1] = __uint_as_float(pv.z);
                }
                __syncthreads();   // the only barrier per step

                // ---- prefetch next step's xg into regs (overlaps matvec) ----
                float xn = 0.f;
                if (lane < 8 && lt + 1 < CH)
                    xn = xg[(size_t)(lt + 1) * G4 + (lane & 3) * H_DIM + gj0 + (lane >> 2)];

                // ---- matvec: 4 gate rows of gj0 and gj0+1 (shared LDS reads) ----
                float a0 = 0.f, a1 = 0.f, a2 = 0.f, a3 = 0.f;
                float a4 = 0.f, a5 = 0.f, a6 = 0.f, a7 = 0.f;
#pragma unroll
                for (int m = 0; m < 16; ++m) {
                    float hvv = hs[p][lane + (m << 6)];
                    a0 = fmaf(Wreg0[0][m], hvv, a0);
                    a1 = fmaf(Wreg0[1][m], hvv, a1);
                    a2 = fmaf(Wreg0[2][m], hvv, a2);
                    a3 = fmaf(Wreg0[3][m], hvv, a3);
                    a4 = fmaf(Wreg1[0][m], hvv, a4);
                    a5 = fmaf(Wreg1[1][m], hvv, a5);
                    a6 = fmaf(Wreg1[2][m], hvv, a6);
                    a7 = fmaf(Wreg1[3][m], hvv, a7);
                }
                // xor-tree reduce: 32,16 via shfl; 8 via DPP row_ror:8; 4 via
                // shfl; 2,1 via DPP quad_perm. Same pairs, same order ->
                // bitwise identical; all lanes end with the full sums.
                a0 += __shfl_xor(a0, 32); a1 += __shfl_xor(a1, 32);
                a2 += __shfl_xor(a2, 32); a3 += __shfl_xor(a3, 32);
                a4 += __shfl_xor(a4, 32); a5 += __shfl_xor(a5, 32);
                a6 += __shfl_xor(a6, 32); a7 += __shfl_xor(a7, 32);
                a0 += __shfl_xor(a0, 16); a1 += __shfl_xor(a1, 16);
                a2 += __shfl_xor(a2, 16); a3 += __shfl_xor(a3, 16);
                a4 += __shfl_xor(a4, 16); a5 += __shfl_xor(a5, 16);
                a6 += __shfl_xor(a6, 16); a7 += __shfl_xor(a7, 16);
                a0 += dpp_xor<0x128>(a0); a1 += dpp_xor<0x128>(a1);
                a2 += dpp_xor<0x128>(a2); a3 += dpp_xor<0x128>(a3);
                a4 += dpp_xor<0x128>(a4); a5 += dpp_xor<0x128>(a5);
                a6 += dpp_xor<0x128>(a6); a7 += dpp_xor<0x128>(a7);
                a0 += __shfl_xor(a0, 4);  a1 += __shfl_xor(a1, 4);
                a2 += __shfl_xor(a2, 4);  a3 += __shfl_xor(a3, 4);
                a4 += __shfl_xor(a4, 4);  a5 += __shfl_xor(a5, 4);
                a6 += __shfl_xor(a6, 4);  a7 += __shfl_xor(a7, 4);
                a0 += dpp_xor<0x4E>(a0);  a1 += dpp_xor<0x4E>(a1);
                a2 += dpp_xor<0x4E>(a2);  a3 += dpp_xor<0x4E>(a3);
                a4 += dpp_xor<0x4E>(a4);  a5 += dpp_xor<0x4E>(a5);
                a6 += dpp_xor<0x4E>(a6);  a7 += dpp_xor<0x4E>(a7);
                a0 += dpp_xor<0xB1>(a0);  a1 += dpp_xor<0xB1>(a1);
                a2 += dpp_xor<0xB1>(a2);  a3 += dpp_xor<0xB1>(a3);
                a4 += dpp_xor<0xB1>(a4);  a5 += dpp_xor<0xB1>(a5);
                a6 += dpp_xor<0xB1>(a6);  a7 += dpp_xor<0xB1>(a7);

                // ---- all-lane activations, both elements (bitwise same) ----
                float x0 = a0 + xv0, x1 = a1 + xv1, x2 = a2 + xv2, x3 = a3 + xv3;
                float y0 = a4 + xv4, y1 = a5 + xv5, y2 = a6 + xv6, y3 = a7 + xv7;
                float i0  = 1.f / (1.f + __expf(-x0));
                float f0  = 1.f / (1.f + __expf(-x1));
                float s0  = 1.f / (1.f + __expf(-2.f * x2));
                float g0  = fmaf(s0, 2.f, -1.f);
                float o0  = 1.f / (1.f + __expf(-x3));
                c0s = fmaf(f0, c0s, i0 * g0);
                float t0c = 2.f / (1.f + __expf(-2.f * c0s)) - 1.f;
                float h0  = o0 * t0c;
                float i1  = 1.f / (1.f + __expf(-y0));
                float f1  = 1.f / (1.f + __expf(-y1));
                float s1  = 1.f / (1.f + __expf(-2.f * y2));
                float g1  = fmaf(s1, 2.f, -1.f);
                float o1  = 1.f / (1.f + __expf(-y3));
                c1s = fmaf(f1, c1s, i1 * g1);
                float t1c = 2.f / (1.f + __expf(-2.f * c1s)) - 1.f;
                float h1  = o1 * t1c;

                if (lane == 0) {
                    // publish ASAP: both elements, ONE 16B store (tag t+2,
                    // slot (t+1)&3); each 8B half is whole (no tearing)
                    uintx4 st;
                    st.x = __float_as_uint(h0); st.y = (unsigned)(t + 2);
                    st.z = __float_as_uint(h1); st.w = (unsigned)(t + 2);
                    unsigned long long* pp =
                        hslot + ((size_t)((t + 1) & 3) << 10) + gj0;
                    asm volatile("global_store_dwordx4 %0, %1, off sc0 sc1"
                                 :: "v"(pp), "v"(st) : "memory");
                    // post-publish tail (off the publish critical path)
                    ered[t & 15][2 * j]     = __expf(h0);   // h in (-1,1): safe
                    ered[t & 15][2 * j + 1] = __expf(h1);
                    if (gj0 == yt)     hy[t] = h0;
                    if (gj0 + 1 == yt) hy[t] = h1;
                }

                // ---- batched exp-partial flush: every 4 steps, rotating wave
                //      (moved post-publish, off the critical path) ----
                if ((t & 3) == 0 && t >= 4 && j == ((t >> 2) & 7)) {
                    const int b = t - 4;
                    float e = ered[(b & 15) + (lane >> 4)][lane & 15];
                    e += __shfl_xor(e, 1);
                    e += __shfl_xor(e, 2);
                    e += __shfl_xor(e, 4);
                    e += __shfl_xor(e, 8);
                    if ((lane & 15) == 0)
                        partials[(size_t)w * T_STEPS + b + (lane >> 4)] = e;
                }

                // ---- ys prefetch + xv broadcast (post-publish) ----
                ytn = yt;
                if (lane == 0) {
                    int tn = (t + 1 < T_STEPS) ? t + 1 : t;
                    ytn = ys[tn];
                }
                yt = ytn;
                xv0 = bcast_lane(xn, 0); xv1 = bcast_lane(xn, 1);
                xv2 = bcast_lane(xn, 2); xv3 = bcast_lane(xn, 3);
                xv4 = bcast_lane(xn, 4); xv5 = bcast_lane(xn, 5);
                xv6 = bcast_lane(xn, 6); xv7 = bcast_lane(xn, 7);
            }

            __syncthreads();   // all this wg's xg reads for chunk c retired
            if (tid == 0)
                __hip_atomic_fetch_add(&cons_done[c], 1,
                                       __ATOMIC_RELAXED, __HIP_MEMORY_SCOPE_AGENT);
        }

        // final exp-partial flush (steps T-4 .. T-1)
        __syncthreads();
        if (j == 0) {
            const int b = T_STEPS - 4;
            float e = ered[(b & 15) + (lane >> 4)][lane & 15];
            e += __shfl_xor(e, 1);
            e += __shfl_xor(e, 2);
            e += __shfl_xor(e, 4);
            e += __shfl_xor(e, 8);
            if ((lane & 15) == 0)
                partials[(size_t)w * T_STEPS + b + (lane >> 4)] = e;
        }
    }

    __threadfence();
    grid.sync();

    // ================= loss: wgs 0..31 cover all T =================
    if (w < 32) {
        int t = w * NTH + tid;
        float s = 0.f;
        for (int i = 0; i < NWG_REC; ++i) s += partials[(size_t)i * T_STEPS + t];
        float val = logf(s) - hy[t];
#pragma unroll
        for (int off = 32; off >= 1; off >>= 1) val += __shfl_xor(val, off);
        if (lane == 0) red[tid >> 6] = val;
        __syncthreads();
        if (tid == 0) {
            float s2 = 0.f;
#pragma unroll
            for (int i = 0; i < 8; ++i) s2 += red[i];
            wsum[w] = s2;
        }
    }
    __threadfence();
    grid.sync();
    if (w == 0 && tid == 0) {
        float s = 0.f;
        for (int i = 0; i < 32; ++i) s += wsum[i];
        out[0] = s;
    }
}

// ---------------- launch ----------------
extern "C" void kernel_launch(void* const* d_in, const int* in_sizes, int n_in,
                              void* d_out, int out_size, void* d_ws, size_t ws_size,
                              hipStream_t stream)
{
    const float* Xs  = (const float*)d_in[0];
    const float* Wih = (const float*)d_in[1];
    const float* Whh = (const float*)d_in[2];
    const float* bih = (const float*)d_in[3];
    const float* bhh = (const float*)d_in[4];
    const int*   ys  = (const int*)d_in[5];

    // workspace: 8MB xgc ring + 32KB hslot + 4MB partials + 64KB hy + 128B wsum
    //            + 512B flags ~= 12.1 MiB
    float* xgc                = (float*)d_ws;
    unsigned long long* hslot = (unsigned long long*)(xgc + 2 * (size_t)CH * G4);
    float* partials           = (float*)(hslot + 4 * H_DIM);
    float* hy                 = partials + (size_t)NWG_REC * T_STEPS;
    float* wsum               = hy + T_STEPS;
    int*   flags              = (int*)(wsum + 32);
    float* out                = (float*)d_out;

    void* args[] = {(void*)&Xs, (void*)&Wih, (void*)&Whh, (void*)&bih, (void*)&bhh,
                    (void*)&ys, (void*)&xgc, (void*)&hslot, (void*)&partials,
                    (void*)&hy, (void*)&wsum, (void*)&flags, (void*)&out};
    hipLaunchCooperativeKernel((void*)lstm_fused_kernel,
                               dim3(NWG), dim3(NTH), args, 0, stream);
}

// Round 7
// 30048.511 us; speedup vs baseline: 4.1434x; 1.6878x over previous
//
#include <hip/hip_runtime.h>
#include <hip/hip_cooperative_groups.h>
#include <cstddef>

namespace cg = cooperative_groups;

#define T_STEPS 16384
#define E_DIM   1024
#define H_DIM   1024
#define G4      4096

#define NWG_REC  128        // recurrence workgroups (hot loop)
#define NWG_GEMM 32         // dedicated GEMM producer workgroups
#define NWG      (NWG_REC + NWG_GEMM)
#define NTH      512        // 8 waves per wg
#define EPW      8          // h elements per recurrence wg (one per wave)
#define CH       256        // timesteps per GEMM chunk; ring of 2 => 2*4MiB = 8MiB
#define NCHUNK   (T_STEPS / CH)
#define TKc      32
#define NREP     4          // hslot replicas (address-disjoint, 32KB apart)
#define REPSTRIDE 4096      // entries per replica (4 slots * 1024)

#define LDA(p)    __hip_atomic_load((p), __ATOMIC_RELAXED, __HIP_MEMORY_SCOPE_AGENT)
#define STA(p, v) __hip_atomic_store((p), (v), __ATOMIC_RELAXED, __HIP_MEMORY_SCOPE_AGENT)

typedef unsigned int uintx4 __attribute__((ext_vector_type(4)));

// DPP xor-partner add helpers (quad_perm): bitwise-identical to __shfl_xor at
// offsets 1 (0xB1 = [1,0,3,2]) and 2 (0x4E = [2,3,0,1]) but VALU-speed.
template <int CTRL>
__device__ __forceinline__ float dpp_xor(float v) {
    return __int_as_float(
        __builtin_amdgcn_update_dpp(0, __float_as_int(v), CTRL, 0xF, 0xF, true));
}

// h exchange: h_t at hslot[rep*4096 + (t&3)<<10 | j], value ((t+1)<<32)|bits.
// Tags 1..16385; stale/poison tags never match. Poll = round-2 proven serial
// single-asm-block dwordx4 sc0 sc1 (load + vmcnt(0) in ONE statement).
// REPLICATION (the one change vs the 28.9ms kernel): publisher writes NREP=4
// address-disjoint copies (32KB apart -> distinct LLC slice sets); consumer
// WG w polls copy w&3. Readers per line drop 128->32 and the hot 8KB region
// spreads across 4x the LLC slices -> per-slice response queueing ~/4.

__global__ __launch_bounds__(NTH) void lstm_fused_kernel(
    const float* __restrict__ Xs, const float* __restrict__ Wih,
    const float* __restrict__ Whh, const float* __restrict__ bih,
    const float* __restrict__ bhh, const int* __restrict__ ys,
    float* __restrict__ xgc,                 // 2 * CH * 4096 floats (ring)
    unsigned long long* __restrict__ hslot,  // NREP * 4*1024 packed entries
    float* __restrict__ partials,            // NWG_REC*T
    float* __restrict__ hy,                  // T
    float* __restrict__ wsum,                // 32
    int*   __restrict__ flags,               // [0..63]=chunk_ready [64..127]=cons_done
    float* __restrict__ out)                 // 1
{
    cg::grid_group grid = cg::this_grid();
    const int w    = blockIdx.x;
    const int tid  = threadIdx.x;
    const int lane = tid & 63;
    const int j    = tid >> 6;        // wave index

    __shared__ float hs[2][H_DIM];    // double-buffered h stage
    __shared__ float ered[16][EPW];   // exp partials ring (16 steps deep)
    __shared__ float red[8];
    __shared__ float As[TKc][68];
    __shared__ float Bs[TKc][132];

    int* chunk_ready = flags;
    int* cons_done   = flags + 64;

    // flags must start at 0 regardless of workspace poison / previous run
    if (w == 0 && tid < 128) STA(&flags[tid], 0);
    grid.sync();

    if (w >= NWG_REC) {
        // ================= dedicated GEMM producers =================
        const int g    = w - NWG_REC;       // 0..31 : col tile (128 cols)
        const int n0   = g * 128;
        const int tx4  = (tid & 31) * 4;
        const int ty4  = (tid >> 5) * 4;
        const int lrow = tid >> 3;
        const int lkg  = (tid & 7) * 4;

        float4 bias_v;
        {
            const float4 bi = *(const float4*)&bih[n0 + tx4];
            const float4 bh = *(const float4*)&bhh[n0 + tx4];
            bias_v.x = bi.x + bh.x; bias_v.y = bi.y + bh.y;
            bias_v.z = bi.z + bh.z; bias_v.w = bi.w + bh.w;
        }

        for (int c = 0; c < NCHUNK; ++c) {
            if (c >= 2) {   // ring slot c&1 free only when chunk c-2 consumed
                if (tid == 0) while (LDA(&cons_done[c - 2]) < NWG_REC) {}
                __syncthreads();
            }
            const int t0 = c * CH;
            float* xg = xgc + (size_t)(c & 1) * ((size_t)CH * G4);

#pragma unroll 1
            for (int rep = 0; rep < 4; ++rep) {    // 4 row tiles of 64 = 256 rows
                float acc[4][4];
#pragma unroll
                for (int i = 0; i < 4; ++i)
#pragma unroll
                    for (int jj = 0; jj < 4; ++jj) acc[i][jj] = 0.f;

                const float* Arow = Xs + (size_t)(t0 + rep * 64 + lrow) * E_DIM + lkg;

                for (int kc = 0; kc < E_DIM; kc += TKc) {
                    __syncthreads();
                    float4 av = *(const float4*)(Arow + kc);
                    As[lkg + 0][lrow] = av.x; As[lkg + 1][lrow] = av.y;
                    As[lkg + 2][lrow] = av.z; As[lkg + 3][lrow] = av.w;
#pragma unroll
                    for (int r2 = 0; r2 < 2; ++r2) {
                        int br = r2 * 64 + lrow;
                        float4 bv = *(const float4*)&Wih[(size_t)(n0 + br) * E_DIM + kc + lkg];
                        Bs[lkg + 0][br] = bv.x; Bs[lkg + 1][br] = bv.y;
                        Bs[lkg + 2][br] = bv.z; Bs[lkg + 3][br] = bv.w;
                    }
                    __syncthreads();
#pragma unroll
                    for (int kk = 0; kk < TKc; ++kk) {
                        float4 a = *(const float4*)&As[kk][ty4];
                        float4 b = *(const float4*)&Bs[kk][tx4];
                        acc[0][0] = fmaf(a.x, b.x, acc[0][0]); acc[0][1] = fmaf(a.x, b.y, acc[0][1]);
                        acc[0][2] = fmaf(a.x, b.z, acc[0][2]); acc[0][3] = fmaf(a.x, b.w, acc[0][3]);
                        acc[1][0] = fmaf(a.y, b.x, acc[1][0]); acc[1][1] = fmaf(a.y, b.y, acc[1][1]);
                        acc[1][2] = fmaf(a.y, b.z, acc[1][2]); acc[1][3] = fmaf(a.y, b.w, acc[1][3]);
                        acc[2][0] = fmaf(a.z, b.x, acc[2][0]); acc[2][1] = fmaf(a.z, b.y, acc[2][1]);
                        acc[2][2] = fmaf(a.z, b.z, acc[2][2]); acc[2][3] = fmaf(a.z, b.w, acc[2][3]);
                        acc[3][0] = fmaf(a.w, b.x, acc[3][0]); acc[3][1] = fmaf(a.w, b.y, acc[3][1]);
                        acc[3][2] = fmaf(a.w, b.z, acc[3][2]); acc[3][3] = fmaf(a.w, b.w, acc[3][3]);
                    }
                }
#pragma unroll
                for (int i = 0; i < 4; ++i) {
                    int lr = rep * 64 + ty4 + i;   // chunk-local row
                    float4 ov;
                    ov.x = acc[i][0] + bias_v.x; ov.y = acc[i][1] + bias_v.y;
                    ov.z = acc[i][2] + bias_v.z; ov.w = acc[i][3] + bias_v.w;
                    *(float4*)&xg[(size_t)lr * G4 + n0 + tx4] = ov;
                }
            }
            __syncthreads();   // drains all threads' xg stores to L2
            if (tid == 0)
                __hip_atomic_fetch_add(&chunk_ready[c], 1,
                                       __ATOMIC_RELEASE, __HIP_MEMORY_SCOPE_AGENT);
        }
    } else {
        // ================= recurrence workgroups =================
        const int gj = w * EPW + j;     // global h element this wave owns

        // ---- W_hh rows for the 4 gates of element gj; k = lane + 64m ----
        float Wreg[4][16];
#pragma unroll
        for (int g = 0; g < 4; ++g) {
            const float* wr = Whh + (size_t)(g * H_DIM + gj) * H_DIM + lane;
#pragma unroll
            for (int m = 0; m < 16; ++m) Wreg[g][m] = wr[m << 6];
        }

        float c_state = 0.f;                              // replicated in all lanes
        if (lane == 0) {                                  // publish h_0 = 0 (tag 1)
#pragma unroll
            for (int r = 0; r < NREP; ++r)
                STA(&hslot[(size_t)r * REPSTRIDE + gj], 1ull << 32);
        }

        float xv0 = 0.f, xv1 = 0.f, xv2 = 0.f, xv3 = 0.f; // xg broadcast to all lanes
        int   yt = 0;

        // this WG's poll replica base (WG w reads copy w&3)
        const unsigned long long* hrep = hslot + (size_t)(w & 3) * REPSTRIDE;

        for (int c = 0; c < NCHUNK; ++c) {
            const int t0 = c * CH;
            const float* xg = xgc + (size_t)(c & 1) * ((size_t)CH * G4);

            // wait for producers; per-thread acquire invalidates stale cache lines
            if (tid == 0) while (LDA(&chunk_ready[c]) < NWG_GEMM) {}
            __syncthreads();
            (void)__hip_atomic_load(&chunk_ready[c],
                                    __ATOMIC_ACQUIRE, __HIP_MEMORY_SCOPE_AGENT);

            // xg for first step of chunk (lanes 0..3 load, broadcast to all)
            {
                float xq = 0.f;
                if (lane < 4) xq = xg[lane * H_DIM + gj];
                xv0 = __shfl(xq, 0); xv1 = __shfl(xq, 1);
                xv2 = __shfl(xq, 2); xv3 = __shfl(xq, 3);
            }

            for (int lt = 0; lt < CH; ++lt) {
                const int t = t0 + lt;
                const int p = t & 1;

                if (lane == 0) yt = ys[t];   // off-path; consumed post-publish

                // ---- poll own h pair: ONE dwordx4 sc0 sc1 per thread ----
                {
                    const unsigned htag = (unsigned)(t + 1);
                    const unsigned long long* hp =
                        hrep + ((size_t)(t & 3) << 10) + 2 * tid;
                    uintx4 pv;
                    do {
                        asm volatile(
                            "global_load_dwordx4 %0, %1, off sc0 sc1\n\t"
                            "s_waitcnt vmcnt(0)"
                            : "=&v"(pv) : "v"(hp) : "memory");
                    } while (pv.y != htag || pv.w != htag);
                    hs[p][2 * tid]     = __uint_as_float(pv.x);
                    hs[p][2 * tid + 1] = __uint_as_float(pv.z);
                }
                __syncthreads();   // the only barrier per step

                // ---- batched exp-partial flush: every 8 steps, rotating wave ----
                if ((t & 7) == 0 && t >= 8 && j == ((t >> 3) & 7)) {
                    const int b = t - 8;
                    float e = ered[(b & 15) + (lane >> 3)][lane & 7];
                    e += __shfl_xor(e, 1);
                    e += __shfl_xor(e, 2);
                    e += __shfl_xor(e, 4);
                    if ((lane & 7) == 0)
                        partials[(size_t)w * T_STEPS + b + (lane >> 3)] = e;
                }

                // ---- prefetch next step's xg into regs (off critical path) ----
                float xn = 0.f;
                if (lane < 4 && lt + 1 < CH)
                    xn = xg[(size_t)(lt + 1) * G4 + lane * H_DIM + gj];

                // ---- matvec: 4 gate rows of gj ----
                float a0 = 0.f, a1 = 0.f, a2 = 0.f, a3 = 0.f;
#pragma unroll
                for (int m = 0; m < 16; ++m) {
                    float hvv = hs[p][lane + (m << 6)];
                    a0 = fmaf(Wreg[0][m], hvv, a0);
                    a1 = fmaf(Wreg[1][m], hvv, a1);
                    a2 = fmaf(Wreg[2][m], hvv, a2);
                    a3 = fmaf(Wreg[3][m], hvv, a3);
                }
                // xor-tree reduce: 32,16,8,4 via shfl; 2,1 via DPP (same pairs,
                // same order -> bitwise identical, all lanes get the sums)
#pragma unroll
                for (int off = 32; off >= 4; off >>= 1) {
                    a0 += __shfl_xor(a0, off);
                    a1 += __shfl_xor(a1, off);
                    a2 += __shfl_xor(a2, off);
                    a3 += __shfl_xor(a3, off);
                }
                a0 += dpp_xor<0x4E>(a0); a1 += dpp_xor<0x4E>(a1);
                a2 += dpp_xor<0x4E>(a2); a3 += dpp_xor<0x4E>(a3);
                a0 += dpp_xor<0xB1>(a0); a1 += dpp_xor<0xB1>(a1);
                a2 += dpp_xor<0xB1>(a2); a3 += dpp_xor<0xB1>(a3);

                // ---- all-lane activations (bitwise same formulas as before) ----
                float x0 = a0 + xv0;
                float x1 = a1 + xv1;
                float x2 = a2 + xv2;
                float x3 = a3 + xv3;
                float ii  = 1.f / (1.f + __expf(-x0));
                float ff  = 1.f / (1.f + __expf(-x1));
                float sg2 = 1.f / (1.f + __expf(-2.f * x2));
                float gg  = fmaf(sg2, 2.f, -1.f);
                float oo  = 1.f / (1.f + __expf(-x3));
                c_state   = fmaf(ff, c_state, ii * gg);
                float tc  = 2.f / (1.f + __expf(-2.f * c_state)) - 1.f;
                float h   = oo * tc;

                if (lane == 0) {
                    // publish ASAP: h_{t+1} tag t+2, slot (t+1)&3, all replicas
                    const unsigned long long val =
                        ((unsigned long long)(unsigned)(t + 2) << 32) |
                        (unsigned long long)__float_as_uint(h);
                    const size_t base = ((size_t)((t + 1) & 3) << 10) + gj;
                    STA(&hslot[base],                 val);
                    STA(&hslot[base + REPSTRIDE],     val);
                    STA(&hslot[base + 2 * REPSTRIDE], val);
                    STA(&hslot[base + 3 * REPSTRIDE], val);
                    ered[t & 15][j] = __expf(h);   // h in (-1,1): exp safe
                    if (gj == yt) hy[t] = h;
                }
                xv0 = __shfl(xn, 0); xv1 = __shfl(xn, 1);
                xv2 = __shfl(xn, 2); xv3 = __shfl(xn, 3);
            }

            __syncthreads();   // all this wg's xg reads for chunk c retired
            if (tid == 0)
                __hip_atomic_fetch_add(&cons_done[c], 1,
                                       __ATOMIC_RELAXED, __HIP_MEMORY_SCOPE_AGENT);
        }

        // final exp-partial flush (steps T-8 .. T-1)
        __syncthreads();
        if (j == 0) {
            const int b = T_STEPS - 8;
            float e = ered[(b & 15) + (lane >> 3)][lane & 7];
            e += __shfl_xor(e, 1);
            e += __shfl_xor(e, 2);
            e += __shfl_xor(e, 4);
            if ((lane & 7) == 0)
                partials[(size_t)w * T_STEPS + b + (lane >> 3)] = e;
        }
    }

    __threadfence();
    grid.sync();

    // ================= loss: wgs 0..31 cover all T =================
    if (w < 32) {
        int t = w * NTH + tid;
        float s = 0.f;
        for (int i = 0; i < NWG_REC; ++i) s += partials[(size_t)i * T_STEPS + t];
        float val = logf(s) - hy[t];
#pragma unroll
        for (int off = 32; off >= 1; off >>= 1) val += __shfl_xor(val, off);
        if (lane == 0) red[tid >> 6] = val;
        __syncthreads();
        if (tid == 0) {
            float s2 = 0.f;
#pragma unroll
            for (int i = 0; i < 8; ++i) s2 += red[i];
            wsum[w] = s2;
        }
    }
    __threadfence();
    grid.sync();
    if (w == 0 && tid == 0) {
        float s = 0.f;
        for (int i = 0; i < 32; ++i) s += wsum[i];
        out[0] = s;
    }
}

// ---------------- launch ----------------
extern "C" void kernel_launch(void* const* d_in, const int* in_sizes, int n_in,
                              void* d_out, int out_size, void* d_ws, size_t ws_size,
                              hipStream_t stream)
{
    const float* Xs  = (const float*)d_in[0];
    const float* Wih = (const float*)d_in[1];
    const float* Whh = (const float*)d_in[2];
    const float* bih = (const float*)d_in[3];
    const float* bhh = (const float*)d_in[4];
    const int*   ys  = (const int*)d_in[5];

    // workspace: 8MB xgc ring + 128KB hslot (4 replicas) + 8MB partials
    //            + 64KB hy + 128B wsum + 512B flags ~= 16.2 MiB
    float* xgc                = (float*)d_ws;
    unsigned long long* hslot = (unsigned long long*)(xgc + 2 * (size_t)CH * G4);
    float* partials           = (float*)(hslot + NREP * REPSTRIDE);
    float* hy                 = partials + (size_t)NWG_REC * T_STEPS;
    float* wsum               = hy + T_STEPS;
    int*   flags              = (int*)(wsum + 32);
    float* out                = (float*)d_out;

    void* args[] = {(void*)&Xs, (void*)&Wih, (void*)&Whh, (void*)&bih, (void*)&bhh,
                    (void*)&ys, (void*)&xgc, (void*)&hslot, (void*)&partials,
                    (void*)&hy, (void*)&wsum, (void*)&flags, (void*)&out};
    hipLaunchCooperativeKernel((void*)lstm_fused_kernel,
                               dim3(NWG), dim3(NTH), args, 0, stream);
}